// Round 2
// baseline (244.653 us; speedup 1.0000x reference)
//
#include <hip/hip_runtime.h>

#define BB 32
#define SS 512
#define LL 64
#define TSTART 61
#define TSTOP 62
#define NSEG 16
#define SEGLEN 32
#define QPAD 68   // QT row stride (floats); bank spread ~= stride-1 baseline

typedef short short8 __attribute__((ext_vector_type(8)));
typedef float floatx4 __attribute__((ext_vector_type(4)));

union S8 { int i[4]; short8 v; };

__device__ inline unsigned bf16_rne(float x) {        // round-to-nearest-even
    unsigned u = __float_as_uint(x);
    u += 0x7fffu + ((u >> 16) & 1u);
    return u >> 16;
}
__device__ inline int pack_bf16(float a, float b) {
    return (int)(bf16_rne(a) | (bf16_rne(b) << 16));
}

// 64-bit sentinel: harness ws-poison (fixed byte pattern) cannot plausibly equal it.
#define SENT 0x1B7F5A21C3E49D07ull

// ---------------- Fused kernel ----------------
// Blocks 0..2047: segment producers, one wave each. XCD-affinity remap:
//   physical block p lands on XCD p%8; batch b = (p&7) + 8*((p>>3)>>6) keeps
//   all 64 producers of batch b on XCD b%8. After writing P_seg (row-major)
//   + wsS scale, producer does __threadfence() + agent-release store of SENT
//   into its flag slot wsF[b*64 + 4s+g].
// Blocks 2048..2079 (also XCD b%8): labeled path for batch b, then spin on
//   the 64 flags (agent-acquire), then fold alpha0 through the 16 segment
//   products (combine) — starts as soon as THIS batch's producers finish.
__global__ __launch_bounds__(64) void crf_fused_kernel(
    const float* __restrict__ enc, const float* __restrict__ Tr,
    const int* __restrict__ lens, const int* __restrict__ tags,
    float* __restrict__ wsQ, float* __restrict__ wsS,
    unsigned long long* __restrict__ wsF,
    float* __restrict__ out)
{
    const int blk = blockIdx.x;
    if (blk >= BB * NSEG * 4) {
        // ---------------- labeled path + combine (one wave) ----------------
        const int b = blk - BB * NSEG * 4;
        const int j = threadIdx.x;
        const int len = lens[b];
        const int* tg = tags + b * SS;
        const float* eb = enc + b * (SS * LL);
        float acc = 0.f;
        for (int t = 1 + j; t < len; t += 64) {
            int curt = tg[t], prevt = tg[t - 1];
            acc += Tr[prevt * LL + curt] + eb[t * LL + curt];
        }
        #pragma unroll
        for (int off = 32; off; off >>= 1) acc += __shfl_xor(acc, off);
        if (j == 0) {
            int t0 = tg[0], te = tg[len - 1];
            acc += Tr[TSTART * LL + t0] + eb[t0];
            acc += Tr[te * LL + TSTOP];
            out[BB + b] = acc;
        }

        // ---- combine preamble (independent of producers) ----
        const float* qb = wsQ + (size_t)b * NSEG * 4096;
        float alpha0 = Tr[TSTART * LL + j] + eb[j];
        float m = alpha0;
        #pragma unroll
        for (int off = 32; off; off >>= 1) m = fmaxf(m, __shfl_xor(m, off));
        float a = __expf(alpha0 - m);
        float logscale = m;
        const float trstop = __expf(Tr[j * LL + TSTOP]);

        // ---- wait for this batch's 64 producers ----
        unsigned long long* fl = wsF + (size_t)b * 64;
        while (__hip_atomic_load(&fl[j], __ATOMIC_ACQUIRE,
                                 __HIP_MEMORY_SCOPE_AGENT) != SENT) {
            __builtin_amdgcn_s_sleep(2);
        }
        __threadfence();

        float myscale = wsS[b * (NSEG * 4) + j];   // (s,g) = (j>>2, j&3)

        float A[64], Bv[64];
        #pragma unroll
        for (int i = 0; i < 16; ++i) {             // seg 0: row j, contiguous
            float4 t = *(const float4*)(qb + j * 64 + 4 * i);
            A[4 * i + 0] = t.x; A[4 * i + 1] = t.y; A[4 * i + 2] = t.z; A[4 * i + 3] = t.w;
        }

        auto step = [&](int s, float (&cur)[64]) {
            float l0 = __shfl(myscale, 4 * s + 0);
            float l1 = __shfl(myscale, 4 * s + 1);
            float l2 = __shfl(myscale, 4 * s + 2);
            float l3 = __shfl(myscale, 4 * s + 3);
            float lmax = fmaxf(fmaxf(l0, l1), fmaxf(l2, l3));
            int grp = j >> 4;
            float lgg = (grp == 0) ? l0 : (grp == 1) ? l1 : (grp == 2) ? l2 : l3;
            float at = a * __expf(lgg - lmax);
            int ai = __float_as_int(at);
            float s0 = 0.f, s1 = 0.f, s2 = 0.f, s3 = 0.f;
            #pragma unroll
            for (int c = 0; c < 16; ++c) {
                s0 = fmaf(__int_as_float(__builtin_amdgcn_readlane(ai, 4 * c + 0)), cur[4 * c + 0], s0);
                s1 = fmaf(__int_as_float(__builtin_amdgcn_readlane(ai, 4 * c + 1)), cur[4 * c + 1], s1);
                s2 = fmaf(__int_as_float(__builtin_amdgcn_readlane(ai, 4 * c + 2)), cur[4 * c + 2], s2);
                s3 = fmaf(__int_as_float(__builtin_amdgcn_readlane(ai, 4 * c + 3)), cur[4 * c + 3], s3);
            }
            float an = ((s0 + s1) + (s2 + s3));
            float mx = an;
            #pragma unroll
            for (int off = 32; off; off >>= 1) mx = fmaxf(mx, __shfl_xor(mx, off));
            a = an * (1.0f / mx);
            logscale += lmax + __logf(mx);
        };

        for (int s = 0; s < 16; s += 2) {
            const float* q1 = qb + (size_t)min(s + 1, NSEG - 1) * 4096;
            #pragma unroll
            for (int i = 0; i < 16; ++i) {
                float4 t = *(const float4*)(q1 + j * 64 + 4 * i);
                Bv[4 * i + 0] = t.x; Bv[4 * i + 1] = t.y; Bv[4 * i + 2] = t.z; Bv[4 * i + 3] = t.w;
            }
            step(s, A);
            const float* q2 = qb + (size_t)min(s + 2, NSEG - 1) * 4096;
            #pragma unroll
            for (int i = 0; i < 16; ++i) {
                float4 t = *(const float4*)(q2 + j * 64 + 4 * i);
                A[4 * i + 0] = t.x; A[4 * i + 1] = t.y; A[4 * i + 2] = t.z; A[4 * i + 3] = t.w;
            }
            step(s + 1, Bv);
        }

        float f = a * trstop;
        float ssum = f;
        #pragma unroll
        for (int off = 32; off; off >>= 1) ssum += __shfl_xor(ssum, off);
        if (j == 0) {
            const float LN2x7 = 7.0f * 0.69314718055994530942f;
            out[b] = logscale + (float)(len - 1) * LN2x7 + __logf(ssum);
        }
        return;
    }

    // ---------------- producer path ----------------
    const int lane = threadIdx.x;
    // XCD-affinity remap (bijective): b ≡ blk (mod 8)
    const int xr = blk & 7;
    const int pk = blk >> 3;          // 0..255
    const int b = xr + 8 * (pk >> 6); // 0..31
    const int rem = pk & 63;
    const int s = rem >> 2;           // 0..15
    const int g = rem & 3;            // 0..3
    const int len = lens[b];
    const int q = lane >> 4;
    const int lcol = lane & 15;
    const float* eb = enc + b * (SS * LL);
    const int tlo = SEGLEN * s + 1;
    const int Teff = min(max(len - tlo, 0), SEGLEN);

    float* qdst = wsQ + (size_t)(b * NSEG + s) * 4096;
    unsigned long long* myflag = wsF + (size_t)b * 64 + (4 * s + g);

    if (Teff <= 0) {   // segment entirely past len: transfer = identity (row-major)
        #pragma unroll
        for (int c4 = 0; c4 < 4; ++c4) {
            int c0 = 16 * g + 4 * c4;
            float4 v;
            v.x = (c0 + 0 == lane) ? 1.f : 0.f;
            v.y = (c0 + 1 == lane) ? 1.f : 0.f;
            v.z = (c0 + 2 == lane) ? 1.f : 0.f;
            v.w = (c0 + 3 == lane) ? 1.f : 0.f;
            *(float4*)(qdst + lane * 64 + c0) = v;
        }
        if (lane == 0) wsS[(b * NSEG + s) * 4 + g] = 0.f;
        __threadfence();
        if (lane == 0)
            __hip_atomic_store(myflag, SENT, __ATOMIC_RELEASE, __HIP_MEMORY_SCOPE_AGENT);
        return;
    }

    __shared__ __align__(16) float QT[16 * QPAD];   // running product, [col][row]
    __shared__ __align__(16) float W32[32 * 64];    // staged w vectors, [tt][row]

    // A operand: A[m][k] = E^T[m][k] = exp(T[k][m]) * 2^-7 (bf16, RNE)
    short8 Afr[4][2];
    #pragma unroll
    for (int mt = 0; mt < 4; ++mt)
        #pragma unroll
        for (int c2 = 0; c2 < 2; ++c2) {
            float av[8];
            #pragma unroll
            for (int idx = 0; idx < 8; ++idx) {
                int kk = 32 * c2 + 8 * q + idx;
                int mm = 16 * mt + lcol;
                av[idx] = __expf(Tr[kk * LL + mm]) * 0.0078125f;
            }
            S8 u;
            #pragma unroll
            for (int w2 = 0; w2 < 4; ++w2) u.i[w2] = pack_bf16(av[2 * w2], av[2 * w2 + 1]);
            Afr[mt][c2] = u.v;
        }

    // QT init: M = E^T[:, 16g+lcol]; lane covers rows 16q..16q+15 of its col
    {
        const float* trow = Tr + (16 * g + lcol) * LL;
        #pragma unroll
        for (int u = 0; u < 4; ++u) {
            float4 tv = *(const float4*)(trow + 16 * q + 4 * u);
            float4 ev;
            ev.x = __expf(tv.x) * 0.0078125f;
            ev.y = __expf(tv.y) * 0.0078125f;
            ev.z = __expf(tv.z) * 0.0078125f;
            ev.w = __expf(tv.w) * 0.0078125f;
            *(float4*)(QT + lcol * QPAD + 16 * q + 4 * u) = ev;
        }
    }

    float lg = 0.0f;
    float ecur[8], enxt[8];
    #pragma unroll
    for (int k = 0; k < 8; ++k) ecur[k] = eb[min(tlo + k, SS - 1) * LL + lane];
    #pragma unroll
    for (int k = 0; k < 8; ++k) enxt[k] = eb[min(tlo + 8 + k, SS - 1) * LL + lane];

    for (int cc = 0; cc < 4; ++cc) {
        // stage this chunk's w vectors (rows tt = 8cc..8cc+7) — off critical path
        #pragma unroll
        for (int k = 0; k < 8; ++k) W32[(8 * cc + k) * 64 + lane] = __expf(ecur[k]);
        // prefetch enc chunk cc+2
        float epre[8];
        #pragma unroll
        for (int k = 0; k < 8; ++k) epre[k] = eb[min(tlo + 8 * (cc + 2) + k, SS - 1) * LL + lane];

        #pragma unroll
        for (int k = 0; k < 8; ++k) {
            const int i = 8 * cc + k + 2;     // MFMA step index, 2..33
            if (i <= Teff) {                  // wave-uniform
                const int wloc = 8 * cc + k;  // uses w_{tlo+i-2}
                float4 qv[2][2], wv[2][2];
                #pragma unroll
                for (int c2 = 0; c2 < 2; ++c2)
                    #pragma unroll
                    for (int h = 0; h < 2; ++h) {
                        qv[c2][h] = *(const float4*)(QT + lcol * QPAD + 32 * c2 + 8 * q + 4 * h);
                        wv[c2][h] = *(const float4*)(W32 + wloc * 64 + 32 * c2 + 8 * q + 4 * h);
                    }
                short8 Bfr[2];
                #pragma unroll
                for (int c2 = 0; c2 < 2; ++c2) {
                    float bv[8];
                    bv[0] = qv[c2][0].x * wv[c2][0].x;  bv[1] = qv[c2][0].y * wv[c2][0].y;
                    bv[2] = qv[c2][0].z * wv[c2][0].z;  bv[3] = qv[c2][0].w * wv[c2][0].w;
                    bv[4] = qv[c2][1].x * wv[c2][1].x;  bv[5] = qv[c2][1].y * wv[c2][1].y;
                    bv[6] = qv[c2][1].z * wv[c2][1].z;  bv[7] = qv[c2][1].w * wv[c2][1].w;
                    S8 u;
                    #pragma unroll
                    for (int w2 = 0; w2 < 4; ++w2)
                        u.i[w2] = pack_bf16(bv[2 * w2], bv[2 * w2 + 1]);
                    Bfr[c2] = u.v;
                }
                float ov[4][4];
                #pragma unroll
                for (int mt = 0; mt < 4; ++mt) {
                    floatx4 z = {0.f, 0.f, 0.f, 0.f};
                    z = __builtin_amdgcn_mfma_f32_16x16x32_bf16(Afr[mt][0], Bfr[0], z, 0, 0, 0);
                    z = __builtin_amdgcn_mfma_f32_16x16x32_bf16(Afr[mt][1], Bfr[1], z, 0, 0, 0);
                    ov[mt][0] = z[0]; ov[mt][1] = z[1]; ov[mt][2] = z[2]; ov[mt][3] = z[3];
                }
                if (k == 7) {                 // periodic rescale
                    float mx = ov[0][0];
                    #pragma unroll
                    for (int mt = 0; mt < 4; ++mt)
                        #pragma unroll
                        for (int r = 0; r < 4; ++r) mx = fmaxf(mx, ov[mt][r]);
                    #pragma unroll
                    for (int off = 32; off; off >>= 1) mx = fmaxf(mx, __shfl_xor(mx, off));
                    lg += __logf(mx);
                    float rmx = 1.0f / mx;
                    #pragma unroll
                    for (int mt = 0; mt < 4; ++mt)
                        #pragma unroll
                        for (int r = 0; r < 4; ++r) ov[mt][r] *= rmx;
                }
                #pragma unroll
                for (int mt = 0; mt < 4; ++mt) {
                    float4 sv = make_float4(ov[mt][0], ov[mt][1], ov[mt][2], ov[mt][3]);
                    *(float4*)(QT + lcol * QPAD + 16 * mt + 4 * q) = sv;
                }
            }
        }
        #pragma unroll
        for (int k = 0; k < 8; ++k) { ecur[k] = enxt[k]; enxt[k] = epre[k]; }
    }

    // final row scale by w_{tlo+Teff-1}; transpose through QT; write ROW-major:
    // lane j writes row j (its 16 cols of group g) as 4 x float4 (coalesced 16B/lane)
    {
        const float wj = W32[(Teff - 1) * 64 + lane];
        #pragma unroll
        for (int c4 = 0; c4 < 4; ++c4) {
            float4 o;
            o.x = QT[(4 * c4 + 0) * QPAD + lane] * wj;
            o.y = QT[(4 * c4 + 1) * QPAD + lane] * wj;
            o.z = QT[(4 * c4 + 2) * QPAD + lane] * wj;
            o.w = QT[(4 * c4 + 3) * QPAD + lane] * wj;
            *(float4*)(qdst + lane * 64 + 16 * g + 4 * c4) = o;
        }
    }
    if (lane == 0) wsS[(b * NSEG + s) * 4 + g] = lg;
    __threadfence();
    if (lane == 0)
        __hip_atomic_store(myflag, SENT, __ATOMIC_RELEASE, __HIP_MEMORY_SCOPE_AGENT);
}

// ---------------- Fallback (exact, used if ws too small) ----------------
__global__ __launch_bounds__(256) void crf_kernel_fb(
    const float* __restrict__ enc, const float* __restrict__ Tr,
    const int* __restrict__ lens, const int* __restrict__ tags,
    float* __restrict__ out)
{
    if (blockIdx.x < BB) {
        const int tid = threadIdx.x;
        if (tid >= 64) return;
        const int b = blockIdx.x;
        const int j = tid;
        const int len = lens[b];
        const float* eb = enc + b * (SS * LL);
        float Ecol[LL];
        #pragma unroll
        for (int i = 0; i < LL; ++i) Ecol[i] = __expf(Tr[i * LL + j]) * 0.0078125f;
        float alpha0 = Tr[TSTART * LL + j] + eb[j];
        float m = alpha0;
        #pragma unroll
        for (int off = 32; off; off >>= 1) m = fmaxf(m, __shfl_xor(m, off));
        float a = __expf(alpha0 - m);
        float logscale = m;
        float ecur[4], enext[4];
        #pragma unroll
        for (int k = 0; k < 4; ++k) ecur[k] = eb[k * LL + j];
        #pragma unroll
        for (int k = 0; k < 4; ++k) enext[k] = eb[(4 + k) * LL + j];
        const int nchunk = (len + 3) >> 2;
        for (int c = 0; c < nchunk; ++c) {
            const int cpre = (c + 2 < 128) ? (c + 2) : 127;
            float efar[4];
            #pragma unroll
            for (int k = 0; k < 4; ++k) efar[k] = eb[(4 * cpre + k) * LL + j];
            #pragma unroll
            for (int k = 0; k < 4; ++k) {
                const int t = 4 * c + k;
                if (t >= 1 && t < len) {
                    const float w = __expf(ecur[k]);
                    const int ai = __float_as_int(a);
                    float s0 = 0.f, s1 = 0.f, s2 = 0.f, s3 = 0.f;
                    #pragma unroll
                    for (int qq = 0; qq < 16; ++qq) {
                        s0 = fmaf(__int_as_float(__builtin_amdgcn_readlane(ai, 4 * qq + 0)), Ecol[4 * qq + 0], s0);
                        s1 = fmaf(__int_as_float(__builtin_amdgcn_readlane(ai, 4 * qq + 1)), Ecol[4 * qq + 1], s1);
                        s2 = fmaf(__int_as_float(__builtin_amdgcn_readlane(ai, 4 * qq + 2)), Ecol[4 * qq + 2], s2);
                        s3 = fmaf(__int_as_float(__builtin_amdgcn_readlane(ai, 4 * qq + 3)), Ecol[4 * qq + 3], s3);
                    }
                    a = ((s0 + s1) + (s2 + s3)) * w;
                    if ((t & 7) == 7) {
                        float mm = a;
                        #pragma unroll
                        for (int off = 32; off; off >>= 1) mm = fmaxf(mm, __shfl_xor(mm, off));
                        logscale += __logf(mm);
                        a = a * (1.0f / mm);
                    }
                }
            }
            #pragma unroll
            for (int k = 0; k < 4; ++k) { ecur[k] = enext[k]; enext[k] = efar[k]; }
        }
        float f = a * __expf(Tr[j * LL + TSTOP]);
        float ssum = f;
        #pragma unroll
        for (int off = 32; off; off >>= 1) ssum += __shfl_xor(ssum, off);
        if (j == 0) {
            const float LN2x7 = 7.0f * 0.69314718055994530942f;
            out[b] = logscale + (float)(len - 1) * LN2x7 + __logf(ssum);
        }
    } else {
        const int b = blockIdx.x - BB;
        const int tid = threadIdx.x;
        const int len = lens[b];
        const int* tg = tags + b * SS;
        const float* eb = enc + b * (SS * LL);
        float acc = 0.f;
        for (int t = 1 + tid; t < len; t += 256) {
            int curt = tg[t], prevt = tg[t - 1];
            acc += Tr[prevt * LL + curt] + eb[t * LL + curt];
        }
        #pragma unroll
        for (int off = 32; off; off >>= 1) acc += __shfl_xor(acc, off);
        __shared__ float red[4];
        if ((tid & 63) == 0) red[tid >> 6] = acc;
        __syncthreads();
        if (tid == 0) {
            float tot = (red[0] + red[1]) + (red[2] + red[3]);
            int t0 = tg[0], te = tg[len - 1];
            tot += Tr[TSTART * LL + t0] + eb[t0];
            tot += Tr[te * LL + TSTOP];
            out[BB + b] = tot;
        }
    }
}

extern "C" void kernel_launch(void* const* d_in, const int* in_sizes, int n_in,
                              void* d_out, int out_size, void* d_ws, size_t ws_size,
                              hipStream_t stream) {
    const float* enc  = (const float*)d_in[0];
    const float* Tr   = (const float*)d_in[1];
    const int*   lens = (const int*)d_in[2];
    const int*   tags = (const int*)d_in[3];
    float* out = (float*)d_out;

    const size_t needQ = (size_t)BB * NSEG * 4096 * sizeof(float);       // 8 MB
    const size_t needS = (size_t)BB * NSEG * 4 * sizeof(float);          // 8 KB
    const size_t needF = (size_t)BB * 64 * sizeof(unsigned long long);   // 16 KB
    if (ws_size >= needQ + needS + needF) {
        float* wsQ = (float*)d_ws;
        float* wsS = (float*)((char*)d_ws + needQ);
        unsigned long long* wsF = (unsigned long long*)((char*)d_ws + needQ + needS);
        crf_fused_kernel<<<BB * NSEG * 4 + BB, 64, 0, stream>>>(
            enc, Tr, lens, tags, wsQ, wsS, wsF, out);
    } else {
        crf_kernel_fb<<<2 * BB, 256, 0, stream>>>(enc, Tr, lens, tags, out);
    }
}

// Round 3
// 96.344 us; speedup vs baseline: 2.5394x; 2.5394x over previous
//
#include <hip/hip_runtime.h>
#include <hip/hip_bf16.h>

#define BB 32
#define SS 512
#define LL 64
#define TSTART 61
#define TSTOP 62
#define NSEG 16
#define SEGLEN 32
#define QPAD 68   // QT row stride (floats); bank spread ~= stride-1 baseline
#define AFPAD 36  // AF row stride (ints), 16B-aligned, spreads banks 4l%32

typedef short short8 __attribute__((ext_vector_type(8)));
typedef float floatx4 __attribute__((ext_vector_type(4)));

union S8 { int i[4]; short8 v; };

__device__ inline int pack_bf16(float a, float b) {   // RNE, HW v_cvt_pk_bf16_f32
    __hip_bfloat162 h = __float22bfloat162_rn(make_float2(a, b));
    int r;
    __builtin_memcpy(&r, &h, 4);
    return r;
}

// ---------------- Kernel 1: segment transfer-matrix products ----------------
// Blocks 0..511: one (b,s) per block, 256 threads = 4 waves, wave g handles
//   cols [16g,16g+16). XCD-affinity remap: physical block p lands on XCD p%8;
//   b = (p&7) + 8*((p>>3)>>4), s = (p>>3)&15 keeps all 16 producer blocks of
//   batch b on XCD b%8 (same as combine block b).
//   Shared across the 4 waves (computed cooperatively once per block):
//     AF  = bf16-packed A fragments of E^T (16 exps/thread vs 64)
//     W32 = exp(enc) diag vectors      (2 exps/thread/chunk vs 8)
//     enc loads 4x fewer, Tr loads 4x fewer.
//   Per wave: QT running product in its own LDS slice, 32-step MFMA chain.
//   wsQ layout: ROW-major P (qdst[row*64+col]) for combine's dwordx4 reads.
// Blocks 512..543: labeled path for batch blockIdx-512 (256 threads).
__global__ __launch_bounds__(256) void crf_seg_kernel(
    const float* __restrict__ enc, const float* __restrict__ Tr,
    const int* __restrict__ lens, const int* __restrict__ tags,
    float* __restrict__ wsQ, float* __restrict__ wsS,
    float* __restrict__ out)
{
    const int blk = blockIdx.x;
    const int tid = threadIdx.x;
    if (blk >= BB * NSEG) {
        // ---------------- labeled path (256 threads) ----------------
        const int b = blk - BB * NSEG;
        const int len = lens[b];
        const int* tg = tags + b * SS;
        const float* eb = enc + b * (SS * LL);
        float acc = 0.f;
        for (int t = 1 + tid; t < len; t += 256) {
            int curt = tg[t], prevt = tg[t - 1];
            acc += Tr[prevt * LL + curt] + eb[t * LL + curt];
        }
        #pragma unroll
        for (int off = 32; off; off >>= 1) acc += __shfl_xor(acc, off);
        __shared__ float red[4];
        if ((tid & 63) == 0) red[tid >> 6] = acc;
        __syncthreads();
        if (tid == 0) {
            float tot = (red[0] + red[1]) + (red[2] + red[3]);
            int t0 = tg[0], te = tg[len - 1];
            tot += Tr[TSTART * LL + t0] + eb[t0];
            tot += Tr[te * LL + TSTOP];
            out[BB + b] = tot;
        }
        return;
    }

    // ---------------- producer path ----------------
    const int lane = tid & 63;
    const int g = tid >> 6;           // wave id = column group
    // XCD-affinity remap (bijective): b ≡ blk (mod 8)
    const int xr = blk & 7;
    const int pk = blk >> 3;          // 0..63
    const int b = xr + 8 * (pk >> 4); // 0..31
    const int s = pk & 15;            // 0..15
    const int len = lens[b];
    const int q = lane >> 4;
    const int lcol = lane & 15;
    const float* eb = enc + b * (SS * LL);
    const int tlo = SEGLEN * s + 1;
    const int Teff = min(max(len - tlo, 0), SEGLEN);

    float* qdst = wsQ + (size_t)(b * NSEG + s) * 4096;

    if (Teff <= 0) {   // segment entirely past len: transfer = identity (row-major)
        #pragma unroll
        for (int c4 = 0; c4 < 4; ++c4) {
            int c0 = 16 * g + 4 * c4;
            float4 v;
            v.x = (c0 + 0 == lane) ? 1.f : 0.f;
            v.y = (c0 + 1 == lane) ? 1.f : 0.f;
            v.z = (c0 + 2 == lane) ? 1.f : 0.f;
            v.w = (c0 + 3 == lane) ? 1.f : 0.f;
            *(float4*)(qdst + lane * 64 + c0) = v;
        }
        if (lane == 0) wsS[(b * NSEG + s) * 4 + g] = 0.f;
        return;
    }

    __shared__ __align__(16) float QT_all[4][16 * QPAD];  // per-wave running product, [col][row]
    __shared__ __align__(16) float W32[32 * 64];          // staged w vectors, [tt][row]
    __shared__ __align__(16) int   AF[64 * AFPAD];        // packed bf16 A-fragments, [lane][8 int4]

    float* QT = QT_all[g];

    // Cooperative A-fragment build: thread t packs lane (t&63)'s (mt = t>>6) pair.
    // A[m][k] = E^T[m][k] = exp(T[k][m]) * 2^-7 (bf16 RNE), fragment elem idx:
    //   kk = 32*c2 + 8*q + idx, mm = 16*mt + lcol.
    {
        const int al = tid & 63, amt = tid >> 6;
        const int aq = al >> 4, alc = al & 15;
        #pragma unroll
        for (int c2 = 0; c2 < 2; ++c2) {
            float av[8];
            #pragma unroll
            for (int idx = 0; idx < 8; ++idx)
                av[idx] = __expf(Tr[(32 * c2 + 8 * aq + idx) * LL + 16 * amt + alc]) * 0.0078125f;
            int4 w;
            w.x = pack_bf16(av[0], av[1]);
            w.y = pack_bf16(av[2], av[3]);
            w.z = pack_bf16(av[4], av[5]);
            w.w = pack_bf16(av[6], av[7]);
            *(int4*)(AF + al * AFPAD + (amt * 2 + c2) * 4) = w;
        }
    }

    // QT init: M = E^T[:, 16g+lcol]; lane covers rows 16q..16q+15 of its col
    {
        const float* trow = Tr + (16 * g + lcol) * LL;
        #pragma unroll
        for (int u = 0; u < 4; ++u) {
            float4 tv = *(const float4*)(trow + 16 * q + 4 * u);
            float4 ev;
            ev.x = __expf(tv.x) * 0.0078125f;
            ev.y = __expf(tv.y) * 0.0078125f;
            ev.z = __expf(tv.z) * 0.0078125f;
            ev.w = __expf(tv.w) * 0.0078125f;
            *(float4*)(QT + lcol * QPAD + 16 * q + 4 * u) = ev;
        }
    }

    // enc prefetch pipeline: thread covers chunk elements (row r0, col) and (row r0+4, col)
    const int r0 = tid >> 6;          // 0..3
    const int colt = tid & 63;
    float ecur[2], enxt[2];
    ecur[0] = eb[min(tlo + r0,     SS - 1) * LL + colt];
    ecur[1] = eb[min(tlo + r0 + 4, SS - 1) * LL + colt];
    enxt[0] = eb[min(tlo + 8 + r0,     SS - 1) * LL + colt];
    enxt[1] = eb[min(tlo + 8 + r0 + 4, SS - 1) * LL + colt];

    short8 Afr[4][2];
    float lg = 0.0f;

    for (int cc = 0; cc < 4; ++cc) {
        // stage this chunk's w vectors (rows tt = 8cc..8cc+7), 2 exps/thread
        W32[(8 * cc + r0) * 64 + colt]     = __expf(ecur[0]);
        W32[(8 * cc + 4 + r0) * 64 + colt] = __expf(ecur[1]);
        // prefetch enc chunk cc+2
        float epre[2];
        epre[0] = eb[min(tlo + 8 * (cc + 2) + r0,     SS - 1) * LL + colt];
        epre[1] = eb[min(tlo + 8 * (cc + 2) + r0 + 4, SS - 1) * LL + colt];

        __syncthreads();              // W rows cc (and AF on cc==0) visible

        if (cc == 0) {                // load shared A fragments into registers
            #pragma unroll
            for (int mt = 0; mt < 4; ++mt)
                #pragma unroll
                for (int c2 = 0; c2 < 2; ++c2) {
                    S8 u;
                    *(int4*)u.i = *(const int4*)(AF + lane * AFPAD + (mt * 2 + c2) * 4);
                    Afr[mt][c2] = u.v;
                }
        }

        #pragma unroll
        for (int k = 0; k < 8; ++k) {
            const int i = 8 * cc + k + 2;     // MFMA step index, 2..33
            if (i <= Teff) {                  // block-uniform
                const int wloc = 8 * cc + k;  // uses w_{tlo+i-2}
                float4 qv[2][2], wv[2][2];
                #pragma unroll
                for (int c2 = 0; c2 < 2; ++c2)
                    #pragma unroll
                    for (int h = 0; h < 2; ++h) {
                        qv[c2][h] = *(const float4*)(QT + lcol * QPAD + 32 * c2 + 8 * q + 4 * h);
                        wv[c2][h] = *(const float4*)(W32 + wloc * 64 + 32 * c2 + 8 * q + 4 * h);
                    }
                short8 Bfr[2];
                #pragma unroll
                for (int c2 = 0; c2 < 2; ++c2) {
                    float bv[8];
                    bv[0] = qv[c2][0].x * wv[c2][0].x;  bv[1] = qv[c2][0].y * wv[c2][0].y;
                    bv[2] = qv[c2][0].z * wv[c2][0].z;  bv[3] = qv[c2][0].w * wv[c2][0].w;
                    bv[4] = qv[c2][1].x * wv[c2][1].x;  bv[5] = qv[c2][1].y * wv[c2][1].y;
                    bv[6] = qv[c2][1].z * wv[c2][1].z;  bv[7] = qv[c2][1].w * wv[c2][1].w;
                    S8 u;
                    u.i[0] = pack_bf16(bv[0], bv[1]);
                    u.i[1] = pack_bf16(bv[2], bv[3]);
                    u.i[2] = pack_bf16(bv[4], bv[5]);
                    u.i[3] = pack_bf16(bv[6], bv[7]);
                    Bfr[c2] = u.v;
                }
                float ov[4][4];
                #pragma unroll
                for (int mt = 0; mt < 4; ++mt) {
                    floatx4 z = {0.f, 0.f, 0.f, 0.f};
                    z = __builtin_amdgcn_mfma_f32_16x16x32_bf16(Afr[mt][0], Bfr[0], z, 0, 0, 0);
                    z = __builtin_amdgcn_mfma_f32_16x16x32_bf16(Afr[mt][1], Bfr[1], z, 0, 0, 0);
                    ov[mt][0] = z[0]; ov[mt][1] = z[1]; ov[mt][2] = z[2]; ov[mt][3] = z[3];
                }
                if (k == 7) {                 // periodic rescale
                    float mx = ov[0][0];
                    #pragma unroll
                    for (int mt = 0; mt < 4; ++mt)
                        #pragma unroll
                        for (int r = 0; r < 4; ++r) mx = fmaxf(mx, ov[mt][r]);
                    #pragma unroll
                    for (int off = 32; off; off >>= 1) mx = fmaxf(mx, __shfl_xor(mx, off));
                    lg += __logf(mx);
                    float rmx = 1.0f / mx;
                    #pragma unroll
                    for (int mt = 0; mt < 4; ++mt)
                        #pragma unroll
                        for (int r = 0; r < 4; ++r) ov[mt][r] *= rmx;
                }
                #pragma unroll
                for (int mt = 0; mt < 4; ++mt) {
                    float4 sv = make_float4(ov[mt][0], ov[mt][1], ov[mt][2], ov[mt][3]);
                    *(float4*)(QT + lcol * QPAD + 16 * mt + 4 * q) = sv;
                }
            }
        }
        ecur[0] = enxt[0]; ecur[1] = enxt[1];
        enxt[0] = epre[0]; enxt[1] = epre[1];
    }

    // final row scale by w_{tlo+Teff-1}; transpose through QT; write ROW-major:
    // lane j writes row j (its 16 cols of group g) as 4 x float4 (coalesced 16B/lane)
    {
        const float wj = W32[(Teff - 1) * 64 + lane];
        #pragma unroll
        for (int c4 = 0; c4 < 4; ++c4) {
            float4 o;
            o.x = QT[(4 * c4 + 0) * QPAD + lane] * wj;
            o.y = QT[(4 * c4 + 1) * QPAD + lane] * wj;
            o.z = QT[(4 * c4 + 2) * QPAD + lane] * wj;
            o.w = QT[(4 * c4 + 3) * QPAD + lane] * wj;
            *(float4*)(qdst + lane * 64 + 16 * g + 4 * c4) = o;
        }
    }
    if (lane == 0) wsS[(b * NSEG + s) * 4 + g] = lg;
}

// ---------------- Kernel 2: fold a0 through the 16 segment products ----------------
// One wave per batch. Block b lands on XCD b%8 where its wsQ rows are L2-resident
// (seg kernel's affinity remap). Row-major wsQ: lane j loads its own contiguous
// 256B row via 16 dwordx4 per segment. Two register banks, 1-segment prefetch.
__global__ __launch_bounds__(64) void crf_combine_kernel(
    const float* __restrict__ enc, const float* __restrict__ Tr,
    const int* __restrict__ lens,
    const float* __restrict__ wsQ, const float* __restrict__ wsS,
    float* __restrict__ out)
{
    const int b = blockIdx.x;
    const int j = threadIdx.x;
    const int len = lens[b];
    const float* qb = wsQ + (size_t)b * NSEG * 4096;

    float alpha0 = Tr[TSTART * LL + j] + enc[b * (SS * LL) + j];
    float m = alpha0;
    #pragma unroll
    for (int off = 32; off; off >>= 1) m = fmaxf(m, __shfl_xor(m, off));
    float a = __expf(alpha0 - m);
    float logscale = m;

    float myscale = wsS[b * (NSEG * 4) + j];   // (s,g) = (j>>2, j&3)

    float A[64], Bv[64];
    #pragma unroll
    for (int i = 0; i < 16; ++i) {             // seg 0: row j, contiguous
        float4 t = *(const float4*)(qb + j * 64 + 4 * i);
        A[4 * i + 0] = t.x; A[4 * i + 1] = t.y; A[4 * i + 2] = t.z; A[4 * i + 3] = t.w;
    }

    auto step = [&](int s, float (&cur)[64]) {
        float l0 = __shfl(myscale, 4 * s + 0);
        float l1 = __shfl(myscale, 4 * s + 1);
        float l2 = __shfl(myscale, 4 * s + 2);
        float l3 = __shfl(myscale, 4 * s + 3);
        float lmax = fmaxf(fmaxf(l0, l1), fmaxf(l2, l3));
        int grp = j >> 4;
        float lgg = (grp == 0) ? l0 : (grp == 1) ? l1 : (grp == 2) ? l2 : l3;
        float at = a * __expf(lgg - lmax);
        int ai = __float_as_int(at);
        float s0 = 0.f, s1 = 0.f, s2 = 0.f, s3 = 0.f;
        #pragma unroll
        for (int c = 0; c < 16; ++c) {
            s0 = fmaf(__int_as_float(__builtin_amdgcn_readlane(ai, 4 * c + 0)), cur[4 * c + 0], s0);
            s1 = fmaf(__int_as_float(__builtin_amdgcn_readlane(ai, 4 * c + 1)), cur[4 * c + 1], s1);
            s2 = fmaf(__int_as_float(__builtin_amdgcn_readlane(ai, 4 * c + 2)), cur[4 * c + 2], s2);
            s3 = fmaf(__int_as_float(__builtin_amdgcn_readlane(ai, 4 * c + 3)), cur[4 * c + 3], s3);
        }
        float an = ((s0 + s1) + (s2 + s3));
        float mx = an;
        #pragma unroll
        for (int off = 32; off; off >>= 1) mx = fmaxf(mx, __shfl_xor(mx, off));
        a = an * (1.0f / mx);
        logscale += lmax + __logf(mx);
    };

    for (int s = 0; s < 16; s += 2) {
        const float* q1 = qb + (size_t)min(s + 1, NSEG - 1) * 4096;
        #pragma unroll
        for (int i = 0; i < 16; ++i) {
            float4 t = *(const float4*)(q1 + j * 64 + 4 * i);
            Bv[4 * i + 0] = t.x; Bv[4 * i + 1] = t.y; Bv[4 * i + 2] = t.z; Bv[4 * i + 3] = t.w;
        }
        step(s, A);
        const float* q2 = qb + (size_t)min(s + 2, NSEG - 1) * 4096;
        #pragma unroll
        for (int i = 0; i < 16; ++i) {
            float4 t = *(const float4*)(q2 + j * 64 + 4 * i);
            A[4 * i + 0] = t.x; A[4 * i + 1] = t.y; A[4 * i + 2] = t.z; A[4 * i + 3] = t.w;
        }
        step(s + 1, Bv);
    }

    float f = a * __expf(Tr[j * LL + TSTOP]);
    float ssum = f;
    #pragma unroll
    for (int off = 32; off; off >>= 1) ssum += __shfl_xor(ssum, off);
    if (j == 0) {
        const float LN2x7 = 7.0f * 0.69314718055994530942f;
        out[b] = logscale + (float)(len - 1) * LN2x7 + __logf(ssum);
    }
}

// ---------------- Fallback (exact, used if ws too small) ----------------
__global__ __launch_bounds__(256) void crf_kernel_fb(
    const float* __restrict__ enc, const float* __restrict__ Tr,
    const int* __restrict__ lens, const int* __restrict__ tags,
    float* __restrict__ out)
{
    if (blockIdx.x < BB) {
        const int tid = threadIdx.x;
        if (tid >= 64) return;
        const int b = blockIdx.x;
        const int j = tid;
        const int len = lens[b];
        const float* eb = enc + b * (SS * LL);
        float Ecol[LL];
        #pragma unroll
        for (int i = 0; i < LL; ++i) Ecol[i] = __expf(Tr[i * LL + j]) * 0.0078125f;
        float alpha0 = Tr[TSTART * LL + j] + eb[j];
        float m = alpha0;
        #pragma unroll
        for (int off = 32; off; off >>= 1) m = fmaxf(m, __shfl_xor(m, off));
        float a = __expf(alpha0 - m);
        float logscale = m;
        float ecur[4], enext[4];
        #pragma unroll
        for (int k = 0; k < 4; ++k) ecur[k] = eb[k * LL + j];
        #pragma unroll
        for (int k = 0; k < 4; ++k) enext[k] = eb[(4 + k) * LL + j];
        const int nchunk = (len + 3) >> 2;
        for (int c = 0; c < nchunk; ++c) {
            const int cpre = (c + 2 < 128) ? (c + 2) : 127;
            float efar[4];
            #pragma unroll
            for (int k = 0; k < 4; ++k) efar[k] = eb[(4 * cpre + k) * LL + j];
            #pragma unroll
            for (int k = 0; k < 4; ++k) {
                const int t = 4 * c + k;
                if (t >= 1 && t < len) {
                    const float w = __expf(ecur[k]);
                    const int ai = __float_as_int(a);
                    float s0 = 0.f, s1 = 0.f, s2 = 0.f, s3 = 0.f;
                    #pragma unroll
                    for (int qq = 0; qq < 16; ++qq) {
                        s0 = fmaf(__int_as_float(__builtin_amdgcn_readlane(ai, 4 * qq + 0)), Ecol[4 * qq + 0], s0);
                        s1 = fmaf(__int_as_float(__builtin_amdgcn_readlane(ai, 4 * qq + 1)), Ecol[4 * qq + 1], s1);
                        s2 = fmaf(__int_as_float(__builtin_amdgcn_readlane(ai, 4 * qq + 2)), Ecol[4 * qq + 2], s2);
                        s3 = fmaf(__int_as_float(__builtin_amdgcn_readlane(ai, 4 * qq + 3)), Ecol[4 * qq + 3], s3);
                    }
                    a = ((s0 + s1) + (s2 + s3)) * w;
                    if ((t & 7) == 7) {
                        float mm = a;
                        #pragma unroll
                        for (int off = 32; off; off >>= 1) mm = fmaxf(mm, __shfl_xor(mm, off));
                        logscale += __logf(mm);
                        a = a * (1.0f / mm);
                    }
                }
            }
            #pragma unroll
            for (int k = 0; k < 4; ++k) { ecur[k] = enext[k]; enext[k] = efar[k]; }
        }
        float f = a * __expf(Tr[j * LL + TSTOP]);
        float ssum = f;
        #pragma unroll
        for (int off = 32; off; off >>= 1) ssum += __shfl_xor(ssum, off);
        if (j == 0) {
            const float LN2x7 = 7.0f * 0.69314718055994530942f;
            out[b] = logscale + (float)(len - 1) * LN2x7 + __logf(ssum);
        }
    } else {
        const int b = blockIdx.x - BB;
        const int tid = threadIdx.x;
        const int len = lens[b];
        const int* tg = tags + b * SS;
        const float* eb = enc + b * (SS * LL);
        float acc = 0.f;
        for (int t = 1 + tid; t < len; t += 256) {
            int curt = tg[t], prevt = tg[t - 1];
            acc += Tr[prevt * LL + curt] + eb[t * LL + curt];
        }
        #pragma unroll
        for (int off = 32; off; off >>= 1) acc += __shfl_xor(acc, off);
        __shared__ float red[4];
        if ((tid & 63) == 0) red[tid >> 6] = acc;
        __syncthreads();
        if (tid == 0) {
            float tot = (red[0] + red[1]) + (red[2] + red[3]);
            int t0 = tg[0], te = tg[len - 1];
            tot += Tr[TSTART * LL + t0] + eb[t0];
            tot += Tr[te * LL + TSTOP];
            out[BB + b] = tot;
        }
    }
}

extern "C" void kernel_launch(void* const* d_in, const int* in_sizes, int n_in,
                              void* d_out, int out_size, void* d_ws, size_t ws_size,
                              hipStream_t stream) {
    const float* enc  = (const float*)d_in[0];
    const float* Tr   = (const float*)d_in[1];
    const int*   lens = (const int*)d_in[2];
    const int*   tags = (const int*)d_in[3];
    float* out = (float*)d_out;

    const size_t needQ = (size_t)BB * NSEG * 4096 * sizeof(float);   // 8 MB
    const size_t needS = (size_t)BB * NSEG * 4 * sizeof(float);      // 8 KB
    if (ws_size >= needQ + needS) {
        float* wsQ = (float*)d_ws;
        float* wsS = (float*)((char*)d_ws + needQ);
        crf_seg_kernel<<<BB * NSEG + BB, 256, 0, stream>>>(enc, Tr, lens, tags, wsQ, wsS, out);
        crf_combine_kernel<<<BB, 64, 0, stream>>>(enc, Tr, lens, wsQ, wsS, out);
    } else {
        crf_kernel_fb<<<2 * BB, 256, 0, stream>>>(enc, Tr, lens, tags, out);
    }
}

// Round 4
// 89.323 us; speedup vs baseline: 2.7390x; 1.0786x over previous
//
#include <hip/hip_runtime.h>
#include <hip/hip_bf16.h>

#define BB 32
#define SS 512
#define LL 64
#define TSTART 61
#define TSTOP 62
#define NSEG 16
#define SEGLEN 32
#define AFPAD 36  // AF row stride (ints); 32 used, pad spreads banks

typedef short short4v __attribute__((ext_vector_type(4)));
typedef float floatx4 __attribute__((ext_vector_type(4)));

union S4 { int i[2]; short4v v; };

__device__ inline int pack_bf16(float a, float b) {   // RNE, HW v_cvt_pk_bf16_f32
    __hip_bfloat162 h = __float22bfloat162_rn(make_float2(a, b));
    int r;
    __builtin_memcpy(&r, &h, 4);
    return r;
}

// ---------------- Kernel 1: segment transfer-matrix products ----------------
// Blocks 0..511: one (b,s) per block, 256 threads = 4 waves, wave g handles
//   cols [16g,16g+16). XCD-affinity remap: physical block p lands on XCD p%8;
//   b = (p&7) + 8*((p>>3)>>4), s = (p>>3)&15 keeps all 16 producer blocks of
//   batch b on XCD b%8 (same as combine block b).
//   KEY: running product kept ENTIRELY IN REGISTERS. With 16x16x16 bf16 MFMA,
//   the C fragment granule (row = 4q+reg) IS the B fragment granule (k = 4q+idx),
//   so step t -> t+1 needs no cross-lane / LDS redistribution:
//     C --(x w, pack bf16)--> B of next step, 4 chained MFMAs over K=64.
//   Shared (built once, one barrier): AF = bf16 A-fragments of E^T; W32 = exp(enc).
//   wsQ layout: ROW-major P (qdst[row*64+col]) for combine's dwordx4 reads.
// Blocks 512..543: labeled path for batch blockIdx-512 (256 threads).
__global__ __launch_bounds__(256) void crf_seg_kernel(
    const float* __restrict__ enc, const float* __restrict__ Tr,
    const int* __restrict__ lens, const int* __restrict__ tags,
    float* __restrict__ wsQ, float* __restrict__ wsS,
    float* __restrict__ out)
{
    const int blk = blockIdx.x;
    const int tid = threadIdx.x;
    if (blk >= BB * NSEG) {
        // ---------------- labeled path (256 threads) ----------------
        const int b = blk - BB * NSEG;
        const int len = lens[b];
        const int* tg = tags + b * SS;
        const float* eb = enc + b * (SS * LL);
        float acc = 0.f;
        for (int t = 1 + tid; t < len; t += 256) {
            int curt = tg[t], prevt = tg[t - 1];
            acc += Tr[prevt * LL + curt] + eb[t * LL + curt];
        }
        #pragma unroll
        for (int off = 32; off; off >>= 1) acc += __shfl_xor(acc, off);
        __shared__ float red[4];
        if ((tid & 63) == 0) red[tid >> 6] = acc;
        __syncthreads();
        if (tid == 0) {
            float tot = (red[0] + red[1]) + (red[2] + red[3]);
            int t0 = tg[0], te = tg[len - 1];
            tot += Tr[TSTART * LL + t0] + eb[t0];
            tot += Tr[te * LL + TSTOP];
            out[BB + b] = tot;
        }
        return;
    }

    // ---------------- producer path ----------------
    const int lane = tid & 63;
    const int g = tid >> 6;           // wave id = column group
    // XCD-affinity remap (bijective): b ≡ blk (mod 8)
    const int xr = blk & 7;
    const int pk = blk >> 3;          // 0..63
    const int b = xr + 8 * (pk >> 4); // 0..31
    const int s = pk & 15;            // 0..15
    const int len = lens[b];
    const int q = lane >> 4;
    const int lcol = lane & 15;
    const float* eb = enc + b * (SS * LL);
    const int tlo = SEGLEN * s + 1;
    const int Teff = min(max(len - tlo, 0), SEGLEN);

    float* qdst = wsQ + (size_t)(b * NSEG + s) * 4096;

    if (Teff <= 0) {   // segment entirely past len: transfer = identity (row-major)
        #pragma unroll
        for (int c4 = 0; c4 < 4; ++c4) {
            int c0 = 16 * g + 4 * c4;
            float4 v;
            v.x = (c0 + 0 == lane) ? 1.f : 0.f;
            v.y = (c0 + 1 == lane) ? 1.f : 0.f;
            v.z = (c0 + 2 == lane) ? 1.f : 0.f;
            v.w = (c0 + 3 == lane) ? 1.f : 0.f;
            *(float4*)(qdst + lane * 64 + c0) = v;
        }
        if (lane == 0) wsS[(b * NSEG + s) * 4 + g] = 0.f;
        return;
    }

    __shared__ __align__(16) float W32[32 * 64];    // all staged w vectors, [tt][row]
    __shared__ __align__(16) int   AF[64 * AFPAD];  // packed bf16 A-fragments

    // Stage ALL 32 w rows upfront: thread covers 8 rows of its column.
    {
        const int colt = tid & 63, r8 = tid >> 6;   // r8 = 0..3
        #pragma unroll
        for (int jj = 0; jj < 8; ++jj) {
            int row = r8 * 8 + jj;
            W32[row * 64 + colt] = __expf(eb[min(tlo + row, SS - 1) * LL + colt]);
        }
    }

    // Cooperative A-fragment build (16x16x16 layout: k = 16*kc + 4*q + idx).
    // A[m][k] = E^T[m][k] = exp(T[k][m]) * 2^-7 (bf16 RNE); thread t builds
    // lane (t&63)'s fragments for mt = t>>6.
    {
        const int al = tid & 63, mtT = tid >> 6;
        const int aq = al >> 4, alc = al & 15;
        #pragma unroll
        for (int kc = 0; kc < 4; ++kc) {
            float av[4];
            #pragma unroll
            for (int idx = 0; idx < 4; ++idx)
                av[idx] = __expf(Tr[(16 * kc + 4 * aq + idx) * LL + 16 * mtT + alc]) * 0.0078125f;
            AF[al * AFPAD + mtT * 8 + kc * 2 + 0] = pack_bf16(av[0], av[1]);
            AF[al * AFPAD + mtT * 8 + kc * 2 + 1] = pack_bf16(av[2], av[3]);
        }
    }

    // R init (C-layout, in registers): R[mt][r] = E^T[16mt+4q+r][16g+lcol]
    float R[4][4];
    {
        const float* trow = Tr + (16 * g + lcol) * LL;
        #pragma unroll
        for (int mt = 0; mt < 4; ++mt) {
            float4 tv = *(const float4*)(trow + 16 * mt + 4 * q);
            R[mt][0] = __expf(tv.x) * 0.0078125f;
            R[mt][1] = __expf(tv.y) * 0.0078125f;
            R[mt][2] = __expf(tv.z) * 0.0078125f;
            R[mt][3] = __expf(tv.w) * 0.0078125f;
        }
    }

    __syncthreads();   // W32 + AF visible

    // Load this lane's A fragments (4 mt x 4 kc, short4 each)
    short4v Afr[4][4];
    #pragma unroll
    for (int mt = 0; mt < 4; ++mt)
        #pragma unroll
        for (int kc = 0; kc < 4; ++kc) {
            S4 u;
            u.i[0] = AF[lane * AFPAD + mt * 8 + kc * 2 + 0];
            u.i[1] = AF[lane * AFPAD + mt * 8 + kc * 2 + 1];
            Afr[mt][kc] = u.v;
        }

    // Preload w row 0 in C-layout: wreg[mt] = w[16mt+4q+{0..3}]
    float4 wreg[4];
    #pragma unroll
    for (int mt = 0; mt < 4; ++mt)
        wreg[mt] = *(const float4*)(W32 + 16 * mt + 4 * q);

    float lg = 0.0f;
    const int nst = Teff - 1;   // MFMA steps k = 0..nst-1 (uses w row k)

    #pragma unroll
    for (int k = 0; k < 32; ++k) {
        if (k < nst) {                        // block-uniform
            // B fragments: pack (R * w) in C-layout == B-layout of 16x16x16
            short4v Bfr[4];
            #pragma unroll
            for (int kc = 0; kc < 4; ++kc) {
                float s0 = R[kc][0] * wreg[kc].x, s1 = R[kc][1] * wreg[kc].y;
                float s2 = R[kc][2] * wreg[kc].z, s3 = R[kc][3] * wreg[kc].w;
                S4 u;
                u.i[0] = pack_bf16(s0, s1);
                u.i[1] = pack_bf16(s2, s3);
                Bfr[kc] = u.v;
            }
            // prefetch next step's w (off the dependency chain, hides under MFMA)
            float4 wnx[4];
            {
                const int krow = min(k + 1, 31);
                #pragma unroll
                for (int mt = 0; mt < 4; ++mt)
                    wnx[mt] = *(const float4*)(W32 + krow * 64 + 16 * mt + 4 * q);
            }
            // 4 chained 16x16x16 MFMAs per mt over K=64
            #pragma unroll
            for (int mt = 0; mt < 4; ++mt) {
                floatx4 z = {0.f, 0.f, 0.f, 0.f};
                #pragma unroll
                for (int kc = 0; kc < 4; ++kc)
                    z = __builtin_amdgcn_mfma_f32_16x16x16bf16_1k(Afr[mt][kc], Bfr[kc], z, 0, 0, 0);
                R[mt][0] = z[0]; R[mt][1] = z[1]; R[mt][2] = z[2]; R[mt][3] = z[3];
            }
            if ((k & 7) == 7) {               // periodic rescale
                float mx = R[0][0];
                #pragma unroll
                for (int mt = 0; mt < 4; ++mt)
                    #pragma unroll
                    for (int r = 0; r < 4; ++r) mx = fmaxf(mx, R[mt][r]);
                #pragma unroll
                for (int off = 32; off; off >>= 1) mx = fmaxf(mx, __shfl_xor(mx, off));
                lg += __logf(mx);
                float rmx = 1.0f / mx;
                #pragma unroll
                for (int mt = 0; mt < 4; ++mt)
                    #pragma unroll
                    for (int r = 0; r < 4; ++r) R[mt][r] *= rmx;
            }
            #pragma unroll
            for (int mt = 0; mt < 4; ++mt) wreg[mt] = wnx[mt];
        }
    }

    // Final row scale by w_{tlo+Teff-1}; direct ROW-major stores:
    // fixed (mt,r): 16-lane groups write 64B-contiguous (cols 16g..16g+15).
    #pragma unroll
    for (int mt = 0; mt < 4; ++mt) {
        float4 wl = *(const float4*)(W32 + (Teff - 1) * 64 + 16 * mt + 4 * q);
        qdst[(16 * mt + 4 * q + 0) * 64 + 16 * g + lcol] = R[mt][0] * wl.x;
        qdst[(16 * mt + 4 * q + 1) * 64 + 16 * g + lcol] = R[mt][1] * wl.y;
        qdst[(16 * mt + 4 * q + 2) * 64 + 16 * g + lcol] = R[mt][2] * wl.z;
        qdst[(16 * mt + 4 * q + 3) * 64 + 16 * g + lcol] = R[mt][3] * wl.w;
    }
    if (lane == 0) wsS[(b * NSEG + s) * 4 + g] = lg;
}

// ---------------- Kernel 2: fold a0 through the 16 segment products ----------------
// One wave per batch, on XCD b%8 where wsQ is L2-resident. Row-major wsQ: lane j
// reads its contiguous 256B row via 16 dwordx4 per segment, double-banked.
// Rescale is ballot-gated (rare): growth/step <= ~2^12, gate at 1e28 keeps one
// extra step < f32 max. __all on the low side (STOP/PAD cols are structurally 0).
__global__ __launch_bounds__(64) void crf_combine_kernel(
    const float* __restrict__ enc, const float* __restrict__ Tr,
    const int* __restrict__ lens,
    const float* __restrict__ wsQ, const float* __restrict__ wsS,
    float* __restrict__ out)
{
    const int b = blockIdx.x;
    const int j = threadIdx.x;
    const int len = lens[b];
    const float* qb = wsQ + (size_t)b * NSEG * 4096;

    float alpha0 = Tr[TSTART * LL + j] + enc[b * (SS * LL) + j];
    float m = alpha0;
    #pragma unroll
    for (int off = 32; off; off >>= 1) m = fmaxf(m, __shfl_xor(m, off));
    float a = __expf(alpha0 - m);
    float logscale = m;

    float myscale = wsS[b * (NSEG * 4) + j];   // (s,g) = (j>>2, j&3)

    float A[64], Bv[64];
    #pragma unroll
    for (int i = 0; i < 16; ++i) {             // seg 0: row j, contiguous
        float4 t = *(const float4*)(qb + j * 64 + 4 * i);
        A[4 * i + 0] = t.x; A[4 * i + 1] = t.y; A[4 * i + 2] = t.z; A[4 * i + 3] = t.w;
    }

    // rolling prefetch of per-segment scale factors
    float l0 = __shfl(myscale, 0), l1 = __shfl(myscale, 1);
    float l2 = __shfl(myscale, 2), l3 = __shfl(myscale, 3);

    auto step = [&](int s, float (&cur)[64]) {
        float lmax = fmaxf(fmaxf(l0, l1), fmaxf(l2, l3));
        int grp = j >> 4;
        float lgg = (grp == 0) ? l0 : (grp == 1) ? l1 : (grp == 2) ? l2 : l3;
        // prefetch next segment's scales (independent of the chain)
        int sn = (s + 1 < NSEG) ? s + 1 : NSEG - 1;
        float n0 = __shfl(myscale, 4 * sn + 0), n1 = __shfl(myscale, 4 * sn + 1);
        float n2 = __shfl(myscale, 4 * sn + 2), n3 = __shfl(myscale, 4 * sn + 3);
        float at = a * __expf(lgg - lmax);
        int ai = __float_as_int(at);
        float s0 = 0.f, s1 = 0.f, s2 = 0.f, s3 = 0.f;
        #pragma unroll
        for (int c = 0; c < 16; ++c) {
            s0 = fmaf(__int_as_float(__builtin_amdgcn_readlane(ai, 4 * c + 0)), cur[4 * c + 0], s0);
            s1 = fmaf(__int_as_float(__builtin_amdgcn_readlane(ai, 4 * c + 1)), cur[4 * c + 1], s1);
            s2 = fmaf(__int_as_float(__builtin_amdgcn_readlane(ai, 4 * c + 2)), cur[4 * c + 2], s2);
            s3 = fmaf(__int_as_float(__builtin_amdgcn_readlane(ai, 4 * c + 3)), cur[4 * c + 3], s3);
        }
        float an = ((s0 + s1) + (s2 + s3));
        logscale += lmax;
        if (__any(an > 1e28f) || __all(an < 1e-28f)) {   // rare
            float mx = an;
            #pragma unroll
            for (int off = 32; off; off >>= 1) mx = fmaxf(mx, __shfl_xor(mx, off));
            a = an * (1.0f / mx);
            logscale += __logf(mx);
        } else {
            a = an;
        }
        l0 = n0; l1 = n1; l2 = n2; l3 = n3;
    };

    for (int s = 0; s < 16; s += 2) {
        const float* q1 = qb + (size_t)min(s + 1, NSEG - 1) * 4096;
        #pragma unroll
        for (int i = 0; i < 16; ++i) {
            float4 t = *(const float4*)(q1 + j * 64 + 4 * i);
            Bv[4 * i + 0] = t.x; Bv[4 * i + 1] = t.y; Bv[4 * i + 2] = t.z; Bv[4 * i + 3] = t.w;
        }
        step(s, A);
        const float* q2 = qb + (size_t)min(s + 2, NSEG - 1) * 4096;
        #pragma unroll
        for (int i = 0; i < 16; ++i) {
            float4 t = *(const float4*)(q2 + j * 64 + 4 * i);
            A[4 * i + 0] = t.x; A[4 * i + 1] = t.y; A[4 * i + 2] = t.z; A[4 * i + 3] = t.w;
        }
        step(s + 1, Bv);
    }

    float f = a * __expf(Tr[j * LL + TSTOP]);
    float ssum = f;
    #pragma unroll
    for (int off = 32; off; off >>= 1) ssum += __shfl_xor(ssum, off);
    if (j == 0) {
        const float LN2x7 = 7.0f * 0.69314718055994530942f;
        out[b] = logscale + (float)(len - 1) * LN2x7 + __logf(ssum);
    }
}

// ---------------- Fallback (exact, used if ws too small) ----------------
__global__ __launch_bounds__(256) void crf_kernel_fb(
    const float* __restrict__ enc, const float* __restrict__ Tr,
    const int* __restrict__ lens, const int* __restrict__ tags,
    float* __restrict__ out)
{
    if (blockIdx.x < BB) {
        const int tid = threadIdx.x;
        if (tid >= 64) return;
        const int b = blockIdx.x;
        const int j = tid;
        const int len = lens[b];
        const float* eb = enc + b * (SS * LL);
        float Ecol[LL];
        #pragma unroll
        for (int i = 0; i < LL; ++i) Ecol[i] = __expf(Tr[i * LL + j]) * 0.0078125f;
        float alpha0 = Tr[TSTART * LL + j] + eb[j];
        float m = alpha0;
        #pragma unroll
        for (int off = 32; off; off >>= 1) m = fmaxf(m, __shfl_xor(m, off));
        float a = __expf(alpha0 - m);
        float logscale = m;
        float ecur[4], enext[4];
        #pragma unroll
        for (int k = 0; k < 4; ++k) ecur[k] = eb[k * LL + j];
        #pragma unroll
        for (int k = 0; k < 4; ++k) enext[k] = eb[(4 + k) * LL + j];
        const int nchunk = (len + 3) >> 2;
        for (int c = 0; c < nchunk; ++c) {
            const int cpre = (c + 2 < 128) ? (c + 2) : 127;
            float efar[4];
            #pragma unroll
            for (int k = 0; k < 4; ++k) efar[k] = eb[(4 * cpre + k) * LL + j];
            #pragma unroll
            for (int k = 0; k < 4; ++k) {
                const int t = 4 * c + k;
                if (t >= 1 && t < len) {
                    const float w = __expf(ecur[k]);
                    const int ai = __float_as_int(a);
                    float s0 = 0.f, s1 = 0.f, s2 = 0.f, s3 = 0.f;
                    #pragma unroll
                    for (int qq = 0; qq < 16; ++qq) {
                        s0 = fmaf(__int_as_float(__builtin_amdgcn_readlane(ai, 4 * qq + 0)), Ecol[4 * qq + 0], s0);
                        s1 = fmaf(__int_as_float(__builtin_amdgcn_readlane(ai, 4 * qq + 1)), Ecol[4 * qq + 1], s1);
                        s2 = fmaf(__int_as_float(__builtin_amdgcn_readlane(ai, 4 * qq + 2)), Ecol[4 * qq + 2], s2);
                        s3 = fmaf(__int_as_float(__builtin_amdgcn_readlane(ai, 4 * qq + 3)), Ecol[4 * qq + 3], s3);
                    }
                    a = ((s0 + s1) + (s2 + s3)) * w;
                    if ((t & 7) == 7) {
                        float mm = a;
                        #pragma unroll
                        for (int off = 32; off; off >>= 1) mm = fmaxf(mm, __shfl_xor(mm, off));
                        logscale += __logf(mm);
                        a = a * (1.0f / mm);
                    }
                }
            }
            #pragma unroll
            for (int k = 0; k < 4; ++k) { ecur[k] = enext[k]; enext[k] = efar[k]; }
        }
        float f = a * __expf(Tr[j * LL + TSTOP]);
        float ssum = f;
        #pragma unroll
        for (int off = 32; off; off >>= 1) ssum += __shfl_xor(ssum, off);
        if (j == 0) {
            const float LN2x7 = 7.0f * 0.69314718055994530942f;
            out[b] = logscale + (float)(len - 1) * LN2x7 + __logf(ssum);
        }
    } else {
        const int b = blockIdx.x - BB;
        const int tid = threadIdx.x;
        const int len = lens[b];
        const int* tg = tags + b * SS;
        const float* eb = enc + b * (SS * LL);
        float acc = 0.f;
        for (int t = 1 + tid; t < len; t += 256) {
            int curt = tg[t], prevt = tg[t - 1];
            acc += Tr[prevt * LL + curt] + eb[t * LL + curt];
        }
        #pragma unroll
        for (int off = 32; off; off >>= 1) acc += __shfl_xor(acc, off);
        __shared__ float red[4];
        if ((tid & 63) == 0) red[tid >> 6] = acc;
        __syncthreads();
        if (tid == 0) {
            float tot = (red[0] + red[1]) + (red[2] + red[3]);
            int t0 = tg[0], te = tg[len - 1];
            tot += Tr[TSTART * LL + t0] + eb[t0];
            tot += Tr[te * LL + TSTOP];
            out[BB + b] = tot;
        }
    }
}

extern "C" void kernel_launch(void* const* d_in, const int* in_sizes, int n_in,
                              void* d_out, int out_size, void* d_ws, size_t ws_size,
                              hipStream_t stream) {
    const float* enc  = (const float*)d_in[0];
    const float* Tr   = (const float*)d_in[1];
    const int*   lens = (const int*)d_in[2];
    const int*   tags = (const int*)d_in[3];
    float* out = (float*)d_out;

    const size_t needQ = (size_t)BB * NSEG * 4096 * sizeof(float);   // 8 MB
    const size_t needS = (size_t)BB * NSEG * 4 * sizeof(float);      // 8 KB
    if (ws_size >= needQ + needS) {
        float* wsQ = (float*)d_ws;
        float* wsS = (float*)((char*)d_ws + needQ);
        crf_seg_kernel<<<BB * NSEG + BB, 256, 0, stream>>>(enc, Tr, lens, tags, wsQ, wsS, out);
        crf_combine_kernel<<<BB, 64, 0, stream>>>(enc, Tr, lens, wsQ, wsS, out);
    } else {
        crf_kernel_fb<<<2 * BB, 256, 0, stream>>>(enc, Tr, lens, tags, out);
    }
}